// Round 4
// baseline (200.567 us; speedup 1.0000x reference)
//
#include <hip/hip_runtime.h>

// FastCMIF: sliding-window mutual information via exact integer joint
// histograms (replaces the reference's 256 FFT convolutions).
//
// MI = (1/N)[ sum c_kl ln c_kl - sum c_k ln c_k - sum c_l ln c_l + N ln N ]
// OOB window pixels add 0 (border blocks), reproducing border clip + mask.
//
// R9: k_main is within ~7% of the LDS-atomic pipe floor (R8: 8.55 cyc per
// wave64 ds_add vs ~8 cyc two-bank-pass minimum; occupancy lever spent).
// This round removes the two remaining non-pipe costs:
//  (a) parallel epilogue: all 4 waves compute c*ln(c) partials + coll[16]
//      for their 4 k-rows, stage into the dead hist LDS, wave0 reduces
//      (was: wave0 serial over all 256 cells, ~10% of k_main);
//  (b) launch-side: k_mm1 -> 4 blocks x 1024 thr writing mnmx directly
//      (no global atomics, no init memsets); 5 dispatches -> 3.

#define IMH 384
#define IMW 384
#define TH 48
#define TW 48
#define PAD 24
#define PH 432
#define PIMG (PH*PH)        // 186624
#define NIMGW (PIMG/4)      // 46656 words
#define TOTW (2*NIMGW)      // 93312
#define FLTMAX 3.402823466e+38f
#define LN2F 0.69314718055994530942f

#if __has_builtin(__builtin_amdgcn_alignbyte)
#define ALIGNBYTE(hi,lo,s) __builtin_amdgcn_alignbyte((hi),(lo),(s))
#else
#define ALIGNBYTE(hi,lo,s) ((unsigned)(((((unsigned long long)(hi))<<32)|(unsigned long long)(lo)) >> ((s)*8)))
#endif

// ---- min/max: one block per image/template, writes mnmx directly ----
// mnmx layout (8 u32): [0..3] = min bits {im0, im1, t0, t1}
//                      [4..7] = max bits {im0, im1, t0, t1}
__global__ __launch_bounds__(1024)
void k_mm1(const float* __restrict__ im, const float* __restrict__ tm,
           unsigned* __restrict__ mnmx) {
    int b = blockIdx.x;
    const float* src; int cnt;
    if (b < 2) { src = im + b * (IMH*IMW); cnt = IMH*IMW; }
    else       { src = tm + (b - 2) * (TH*TW); cnt = TH*TW; }
    float mn = FLTMAX, mx = -FLTMAX;
    const float4* s4 = (const float4*)src;
    int n4 = cnt >> 2;                      // 36864 or 576 (both exact)
    for (int i = threadIdx.x; i < n4; i += 1024) {
        float4 v = s4[i];
        mn = fminf(mn, fminf(fminf(v.x, v.y), fminf(v.z, v.w)));
        mx = fmaxf(mx, fmaxf(fmaxf(v.x, v.y), fmaxf(v.z, v.w)));
    }
    for (int o = 32; o > 0; o >>= 1) {
        mn = fminf(mn, __shfl_down(mn, o));
        mx = fmaxf(mx, __shfl_down(mx, o));
    }
    __shared__ float smn[16], smx[16];
    int w = threadIdx.x >> 6;
    if ((threadIdx.x & 63) == 0) { smn[w] = mn; smx[w] = mx; }
    __syncthreads();
    if (threadIdx.x < 16) {
        mn = smn[threadIdx.x]; mx = smx[threadIdx.x];
        for (int o = 8; o > 0; o >>= 1) {
            mn = fminf(mn, __shfl_down(mn, o));
            mx = fmaxf(mx, __shfl_down(mx, o));
        }
        if (threadIdx.x == 0) {
            mnmx[b]     = __float_as_uint(mn);
            mnmx[4 + b] = __float_as_uint(mx);
        }
    }
}

// Fused bin+pad and template pack.
__global__ void k_prep(const float* __restrict__ im, const float* __restrict__ tm,
                       const unsigned* __restrict__ mm,
                       unsigned* __restrict__ pImW, unsigned* __restrict__ pT) {
    int blk = blockIdx.x;
    if (blk < 365) {
        int wi = blk * 256 + threadIdx.x;
        if (wi >= TOTW) return;
        int b = wi / NIMGW;
        int rem4 = (wi - b * NIMGW) * 4;
        int py = rem4 / PH;
        int px = rem4 - py * PH;
        float mn = __uint_as_float(mm[b]), mx = __uint_as_float(mm[4 + b]);
        unsigned word = 0;
        #pragma unroll
        for (int j = 0; j < 4; ++j) {
            int x = px + j;
            unsigned bin = 16u;              // sentinel: outside image
            if (py >= PAD && py < PAD + IMH && x >= PAD && x < PAD + IMW) {
                float v = im[b * (IMH*IMW) + (py - PAD) * IMW + (x - PAD)];
                // replicate reference numerics exactly: sub, IEEE div, mul 15, floor
                float r = (v - mn) / (mx - mn);
                bin = (unsigned)(int)floorf(r * 15.0f);
            }
            word |= bin << (8*j);
        }
        pImW[wi] = word;
    } else {
        for (int t = threadIdx.x; t < 576; t += 256) {
            int b = t / 288, w = t - b * 288;
            float mn = __uint_as_float(mm[2 + b]), mx = __uint_as_float(mm[6 + b]);
            const float* tptr = tm + b * (TH*TW) + w * 8;
            unsigned word = 0;
            #pragma unroll
            for (int j = 0; j < 8; ++j) {
                float r = (tptr[j] - mn) / (mx - mn);
                word |= ((unsigned)(int)floorf(r * 15.0f)) << (4*j);
            }
            pT[b*288 + w] = word;
        }
    }
}

__device__ __forceinline__ void load_row(const uint2* rowp, int r, unsigned (&w)[14]) {
    const uint2* p = rowp + r * (PH / 8);
    #pragma unroll
    for (int i = 0; i < 7; ++i) { uint2 v = p[i]; w[2*i] = v.x; w[2*i+1] = v.y; }
}
__device__ __forceinline__ void load_t(const uint2* tp, int r, unsigned (&t)[6]) {
    const uint2* p = tp + r * 3;
    #pragma unroll
    for (int i = 0; i < 3; ++i) { uint2 v = p[i]; t[2*i] = v.x; t[2*i+1] = v.y; }
}

// One window row: 48 updates, no convergent ops inside the loop.
template<bool BORDER>
__device__ __forceinline__ void do_row(const unsigned (&w)[14], const unsigned (&t)[6],
                                       unsigned* __restrict__ hist, int tid,
                                       unsigned sh, bool sel) {
    unsigned wsel[13];
    #pragma unroll
    for (int i = 0; i < 13; ++i) wsel[i] = sel ? w[i+1] : w[i];
    unsigned a[12];   // a[i] bytes = image bins at window cols 4i..4i+3
    #pragma unroll
    for (int i = 0; i < 12; ++i) a[i] = ALIGNBYTE(wsel[i+1], wsel[i], sh);
    unsigned tq[6];   // once per row: SGPR-ize the (uniform) template words
    #pragma unroll
    for (int j = 0; j < 6; ++j)
        tq[j] = (unsigned)__builtin_amdgcn_readfirstlane((int)t[j]);

    #pragma unroll
    for (int c = 0; c < 48; ++c) {
        unsigned byteval = (a[c >> 2] >> ((c & 3) * 8)) & 0xFFu;  // VALU (v_bfe)
        unsigned l    = (tq[c >> 3] >> ((c & 7) * 4)) & 0xFu;     // SALU (tq uniform)
        unsigned soff = (l >> 2) << 6;                            // SALU
        unsigned sadd = 1u << ((l & 3u) << 3);                    // SALU
        if (BORDER) {
            unsigned bin   = byteval & 15u;
            unsigned adder = (byteval != 16u) ? sadd : 0u;        // v_cmp + cndmask
            atomicAdd(&hist[(bin << 8) + soff + tid], adder);
        } else {
            atomicAdd(&hist[(byteval << 8) + soff + tid], sadd);  // lshl+add3+mov+ds_add
        }
    }
}

// Each wave accumulates its 12-row quarter of the window into the SHARED hist.
template<bool BORDER>
__device__ __forceinline__ void accum_tile(const uint2* rowp, const uint2* tp,
                                           unsigned* __restrict__ hist, int tid,
                                           unsigned sh, bool sel) {
    unsigned w0[14], w1[14], t0[6], t1[6];
    load_row(rowp, 0, w0); load_t(tp, 0, t0);
    #pragma unroll 1
    for (int r = 0; r < 12; r += 2) {
        load_row(rowp, r + 1, w1); load_t(tp, r + 1, t1);   // r+1 <= 11 always
        do_row<BORDER>(w0, t0, hist, tid, sh, sel);
        if (r + 2 < 12) { load_row(rowp, r + 2, w0); load_t(tp, r + 2, t0); }
        do_row<BORDER>(w1, t1, hist, tid, sh, sel);
    }
}

__global__ __launch_bounds__(256, 4)
void k_main(const unsigned char* __restrict__ pIm, const unsigned* __restrict__ pT,
            float* __restrict__ out) {
    // u8-packed per-lane joint histograms: word = (bin*4 + l/4)*64 + tid,
    // byte = l&3. ONE 16 KiB histogram shared by all four waves; wave wv
    // accumulates window rows [12*wv, 12*wv+12).
    __shared__ unsigned hist[16 * 4 * 64];
    const int wv  = threadIdx.x >> 6;
    const int tid = threadIdx.x & 63;
    const int tx = tid & 7, ty = tid >> 3;
    const int b = blockIdx.z;
    const int X0 = blockIdx.x << 3, Y0 = blockIdx.y << 3;

    {   // zero; each wave clears a quarter; lane stride 4 words -> max 8-way
        uint4 z = {0u, 0u, 0u, 0u};
        #pragma unroll
        for (int i = 0; i < 4; ++i) ((uint4*)hist)[(wv * 4 + i) * 64 + tid] = z;
    }
    __syncthreads();

    const uint2* rowp = (const uint2*)(pIm + b * PIMG + (Y0 + ty + 12 * wv) * PH + X0);
    const uint2* tp   = (const uint2*)(pT + b * 288) + wv * 36;   // 3 uint2 per t-row
    const unsigned sh = tx & 3;
    const bool sel = (tx & 4) != 0;

    // interior iff no touched padded col/row can be sentinel: [X0,X0+56) in [24,408)
    const bool interior = (blockIdx.x >= 3) && (blockIdx.x <= 43) &&
                          (blockIdx.y >= 3) && (blockIdx.y <= 43);
    if (interior) accum_tile<false>(rowp, tp, hist, tid, sh, sel);
    else          accum_tile<true >(rowp, tp, hist, tid, sh, sel);

    __syncthreads();          // drains all waves' ds_adds (lgkmcnt) + orders

    // ---- parallel epilogue ----
    // Phase 1: wave wv reads its 4 k-rows (k = 4*wv..4*wv+3), computes the
    // joint partial Aw = sum c*log2(c) - sum rk*log2(rk) and the per-wave
    // column-marginal partial colli[16] (each <= 576, fits u16).
    float Aw = 0.0f;
    int colli[16];
    #pragma unroll
    for (int i = 0; i < 16; ++i) colli[i] = 0;
    #pragma unroll
    for (int kk = 0; kk < 4; ++kk) {
        int k = (wv << 2) + kk;
        int rk = 0;
        #pragma unroll
        for (int q = 0; q < 4; ++q) {
            unsigned v = hist[(k << 8) + (q << 6) + tid];
            #pragma unroll
            for (int j = 0; j < 4; ++j) {
                int c = (int)((v >> (8*j)) & 0xFFu);
                rk += c;
                colli[(q << 2) + j] += c;
                if (c) Aw += (float)c * __log2f((float)c);
            }
        }
        if (rk) Aw -= (float)rk * __log2f((float)rk);
    }
    __syncthreads();   // ALL reads complete before hist is reused below

    // Phase 2: stage partials into the (dead) hist LDS.
    // coll words: [wv*512, wv*512+512)   (u16 pairs, 8 words/lane)
    // Aw bits:    [2048 + wv*64, +64)
    #pragma unroll
    for (int j = 0; j < 8; ++j)
        hist[(wv << 9) + (j << 6) + tid] =
            (unsigned)colli[2*j] | ((unsigned)colli[2*j+1] << 16);
    hist[2048 + (wv << 6) + tid] = __float_as_uint(Aw);
    __syncthreads();
    if (wv != 0) return;      // waves 1..3 done

    // Phase 3: wave0 reduces 4 partials per lane and finishes.
    float A = 0.0f;
    #pragma unroll
    for (int w = 0; w < 4; ++w) A += __uint_as_float(hist[2048 + (w << 6) + tid]);
    int coll[16];
    #pragma unroll
    for (int i = 0; i < 16; ++i) coll[i] = 0;
    #pragma unroll
    for (int w = 0; w < 4; ++w) {
        #pragma unroll
        for (int j = 0; j < 8; ++j) {
            unsigned u = hist[(w << 9) + (j << 6) + tid];
            coll[2*j]   += (int)(u & 0xFFFFu);
            coll[2*j+1] += (int)(u >> 16);
        }
    }
    int N = 0;
    #pragma unroll
    for (int i = 0; i < 16; ++i) {
        N += coll[i];
        if (coll[i]) A -= (float)coll[i] * __log2f((float)coll[i]);
    }
    float fN = (float)N;
    out[(b * IMH + Y0 + ty) * IMW + X0 + tx] = (A + fN * __log2f(fN)) * LN2F / fN;
}

extern "C" void kernel_launch(void* const* d_in, const int* in_sizes, int n_in,
                              void* d_out, int out_size, void* d_ws, size_t ws_size,
                              hipStream_t stream) {
    const float* im = (const float*)d_in[0];
    const float* tm = (const float*)d_in[1];
    float* out = (float*)d_out;
    unsigned char* pIm = (unsigned char*)d_ws;             // 373248 B
    unsigned* pT   = (unsigned*)((char*)d_ws + 373248);    // 2304 B
    unsigned* mnmx = (unsigned*)((char*)d_ws + 375552);    // 32 B

    k_mm1<<<4, 1024, 0, stream>>>(im, tm, mnmx);
    k_prep<<<366, 256, 0, stream>>>(im, tm, mnmx, (unsigned*)pIm, pT);
    k_main<<<dim3(48, 48, 2), 256, 0, stream>>>(pIm, pT, out);
}

// Round 5
// 191.805 us; speedup vs baseline: 1.0457x; 1.0457x over previous
//
#include <hip/hip_runtime.h>

// FastCMIF: sliding-window mutual information via exact integer joint
// histograms (replaces the reference's 256 FFT convolutions).
//
// MI = (1/N)[ sum c_kl ln c_kl - sum c_k ln c_k - sum c_l ln c_l + N ln N ]
// OOB window pixels add 0 (border blocks), reproducing border clip + mask.
//
// R10: k_main is at ~96% of the LDS-atomic pipe floor (8.37 vs ~8 cyc per
// wave64 ds_add) -- left untouched. R9's 4-block k_mm1 was latency-bound
// (~25us: 590KB HBM on ONE CU at ~10B/cyc). Restored the wide 68-block
// partial-reduce + 1-block k_mm2 finish (R5 scheme: partials overlap pIm,
// consumed by k_mm2 before k_prep overwrites; stream order guarantees it).
// Dispatch-count deltas measured noise-level across R5-R9; kernel width is
// what matters on the launch side.

#define IMH 384
#define IMW 384
#define TH 48
#define TW 48
#define PAD 24
#define PH 432
#define PIMG (PH*PH)        // 186624
#define NIMGW (PIMG/4)      // 46656 words
#define TOTW (2*NIMGW)      // 93312
#define FLTMAX 3.402823466e+38f
#define LN2F 0.69314718055994530942f

#if __has_builtin(__builtin_amdgcn_alignbyte)
#define ALIGNBYTE(hi,lo,s) __builtin_amdgcn_alignbyte((hi),(lo),(s))
#else
#define ALIGNBYTE(hi,lo,s) ((unsigned)(((((unsigned long long)(hi))<<32)|(unsigned long long)(lo)) >> ((s)*8)))
#endif

// ---- stage 1: wide min/max partial reduction (68 blocks, float4 loads) ----
__global__ void k_mm1(const float* __restrict__ im, const float* __restrict__ tm,
                      float2* __restrict__ partials) {
    int b = blockIdx.x;
    const float4* src; int cnt;
    if (b < 64) { src = (const float4*)(im + (b >> 5) * (IMH*IMW)) + (b & 31) * 1152; cnt = 1152; }
    else        { src = (const float4*)(tm + ((b - 64) >> 1) * (TH*TW)) + ((b - 64) & 1) * 288; cnt = 288; }
    float mn = FLTMAX, mx = -FLTMAX;
    for (int i = threadIdx.x; i < cnt; i += 256) {
        float4 v = src[i];
        mn = fminf(mn, fminf(fminf(v.x, v.y), fminf(v.z, v.w)));
        mx = fmaxf(mx, fmaxf(fmaxf(v.x, v.y), fmaxf(v.z, v.w)));
    }
    for (int o = 32; o > 0; o >>= 1) {
        mn = fminf(mn, __shfl_down(mn, o));
        mx = fmaxf(mx, __shfl_down(mx, o));
    }
    __shared__ float smn[4], smx[4];
    int w = threadIdx.x >> 6;
    if ((threadIdx.x & 63) == 0) { smn[w] = mn; smx[w] = mx; }
    __syncthreads();
    if (threadIdx.x == 0) {
        mn = fminf(fminf(smn[0], smn[1]), fminf(smn[2], smn[3]));
        mx = fmaxf(fmaxf(smx[0], smx[1]), fmaxf(smx[2], smx[3]));
        partials[b] = make_float2(mn, mx);
    }
}

// ---- stage 2: final reduce ----
// mnmx layout (8 u32): [0..3] = min bits {im0, im1, t0, t1}
//                      [4..7] = max bits {im0, im1, t0, t1}
__global__ void k_mm2(const float2* __restrict__ partials, unsigned* __restrict__ mnmx) {
    int w = threadIdx.x >> 6, lane = threadIdx.x & 63;
    int cnt = (w < 2) ? 32 : 2;
    int idx = (w < 2) ? w * 32 + lane : 64 + (w - 2) * 2 + lane;
    float mn = FLTMAX, mx = -FLTMAX;
    if (lane < cnt) { float2 p = partials[idx]; mn = p.x; mx = p.y; }
    for (int o = 32; o > 0; o >>= 1) {
        mn = fminf(mn, __shfl_down(mn, o));
        mx = fmaxf(mx, __shfl_down(mx, o));
    }
    if (lane == 0) { mnmx[w] = __float_as_uint(mn); mnmx[4 + w] = __float_as_uint(mx); }
}

// Fused bin+pad and template pack.
__global__ void k_prep(const float* __restrict__ im, const float* __restrict__ tm,
                       const unsigned* __restrict__ mm,
                       unsigned* __restrict__ pImW, unsigned* __restrict__ pT) {
    int blk = blockIdx.x;
    if (blk < 365) {
        int wi = blk * 256 + threadIdx.x;
        if (wi >= TOTW) return;
        int b = wi / NIMGW;
        int rem4 = (wi - b * NIMGW) * 4;
        int py = rem4 / PH;
        int px = rem4 - py * PH;
        float mn = __uint_as_float(mm[b]), mx = __uint_as_float(mm[4 + b]);
        unsigned word = 0;
        #pragma unroll
        for (int j = 0; j < 4; ++j) {
            int x = px + j;
            unsigned bin = 16u;              // sentinel: outside image
            if (py >= PAD && py < PAD + IMH && x >= PAD && x < PAD + IMW) {
                float v = im[b * (IMH*IMW) + (py - PAD) * IMW + (x - PAD)];
                // replicate reference numerics exactly: sub, IEEE div, mul 15, floor
                float r = (v - mn) / (mx - mn);
                bin = (unsigned)(int)floorf(r * 15.0f);
            }
            word |= bin << (8*j);
        }
        pImW[wi] = word;
    } else {
        for (int t = threadIdx.x; t < 576; t += 256) {
            int b = t / 288, w = t - b * 288;
            float mn = __uint_as_float(mm[2 + b]), mx = __uint_as_float(mm[6 + b]);
            const float* tptr = tm + b * (TH*TW) + w * 8;
            unsigned word = 0;
            #pragma unroll
            for (int j = 0; j < 8; ++j) {
                float r = (tptr[j] - mn) / (mx - mn);
                word |= ((unsigned)(int)floorf(r * 15.0f)) << (4*j);
            }
            pT[b*288 + w] = word;
        }
    }
}

__device__ __forceinline__ void load_row(const uint2* rowp, int r, unsigned (&w)[14]) {
    const uint2* p = rowp + r * (PH / 8);
    #pragma unroll
    for (int i = 0; i < 7; ++i) { uint2 v = p[i]; w[2*i] = v.x; w[2*i+1] = v.y; }
}
__device__ __forceinline__ void load_t(const uint2* tp, int r, unsigned (&t)[6]) {
    const uint2* p = tp + r * 3;
    #pragma unroll
    for (int i = 0; i < 3; ++i) { uint2 v = p[i]; t[2*i] = v.x; t[2*i+1] = v.y; }
}

// One window row: 48 updates, no convergent ops inside the loop.
template<bool BORDER>
__device__ __forceinline__ void do_row(const unsigned (&w)[14], const unsigned (&t)[6],
                                       unsigned* __restrict__ hist, int tid,
                                       unsigned sh, bool sel) {
    unsigned wsel[13];
    #pragma unroll
    for (int i = 0; i < 13; ++i) wsel[i] = sel ? w[i+1] : w[i];
    unsigned a[12];   // a[i] bytes = image bins at window cols 4i..4i+3
    #pragma unroll
    for (int i = 0; i < 12; ++i) a[i] = ALIGNBYTE(wsel[i+1], wsel[i], sh);
    unsigned tq[6];   // once per row: SGPR-ize the (uniform) template words
    #pragma unroll
    for (int j = 0; j < 6; ++j)
        tq[j] = (unsigned)__builtin_amdgcn_readfirstlane((int)t[j]);

    #pragma unroll
    for (int c = 0; c < 48; ++c) {
        unsigned byteval = (a[c >> 2] >> ((c & 3) * 8)) & 0xFFu;  // VALU (v_bfe)
        unsigned l    = (tq[c >> 3] >> ((c & 7) * 4)) & 0xFu;     // SALU (tq uniform)
        unsigned soff = (l >> 2) << 6;                            // SALU
        unsigned sadd = 1u << ((l & 3u) << 3);                    // SALU
        if (BORDER) {
            unsigned bin   = byteval & 15u;
            unsigned adder = (byteval != 16u) ? sadd : 0u;        // v_cmp + cndmask
            atomicAdd(&hist[(bin << 8) + soff + tid], adder);
        } else {
            atomicAdd(&hist[(byteval << 8) + soff + tid], sadd);  // lshl+add3+mov+ds_add
        }
    }
}

// Each wave accumulates its 12-row quarter of the window into the SHARED hist.
template<bool BORDER>
__device__ __forceinline__ void accum_tile(const uint2* rowp, const uint2* tp,
                                           unsigned* __restrict__ hist, int tid,
                                           unsigned sh, bool sel) {
    unsigned w0[14], w1[14], t0[6], t1[6];
    load_row(rowp, 0, w0); load_t(tp, 0, t0);
    #pragma unroll 1
    for (int r = 0; r < 12; r += 2) {
        load_row(rowp, r + 1, w1); load_t(tp, r + 1, t1);   // r+1 <= 11 always
        do_row<BORDER>(w0, t0, hist, tid, sh, sel);
        if (r + 2 < 12) { load_row(rowp, r + 2, w0); load_t(tp, r + 2, t0); }
        do_row<BORDER>(w1, t1, hist, tid, sh, sel);
    }
}

__global__ __launch_bounds__(256, 4)
void k_main(const unsigned char* __restrict__ pIm, const unsigned* __restrict__ pT,
            float* __restrict__ out) {
    // u8-packed per-lane joint histograms: word = (bin*4 + l/4)*64 + tid,
    // byte = l&3. ONE 16 KiB histogram shared by all four waves; wave wv
    // accumulates window rows [12*wv, 12*wv+12).
    __shared__ unsigned hist[16 * 4 * 64];
    const int wv  = threadIdx.x >> 6;
    const int tid = threadIdx.x & 63;
    const int tx = tid & 7, ty = tid >> 3;
    const int b = blockIdx.z;
    const int X0 = blockIdx.x << 3, Y0 = blockIdx.y << 3;

    {   // zero; each wave clears a quarter; lane stride 4 words -> max 8-way
        uint4 z = {0u, 0u, 0u, 0u};
        #pragma unroll
        for (int i = 0; i < 4; ++i) ((uint4*)hist)[(wv * 4 + i) * 64 + tid] = z;
    }
    __syncthreads();

    const uint2* rowp = (const uint2*)(pIm + b * PIMG + (Y0 + ty + 12 * wv) * PH + X0);
    const uint2* tp   = (const uint2*)(pT + b * 288) + wv * 36;   // 3 uint2 per t-row
    const unsigned sh = tx & 3;
    const bool sel = (tx & 4) != 0;

    // interior iff no touched padded col/row can be sentinel: [X0,X0+56) in [24,408)
    const bool interior = (blockIdx.x >= 3) && (blockIdx.x <= 43) &&
                          (blockIdx.y >= 3) && (blockIdx.y <= 43);
    if (interior) accum_tile<false>(rowp, tp, hist, tid, sh, sel);
    else          accum_tile<true >(rowp, tp, hist, tid, sh, sel);

    __syncthreads();          // drains all waves' ds_adds (lgkmcnt) + orders

    // ---- parallel epilogue ----
    // Phase 1: wave wv reads its 4 k-rows (k = 4*wv..4*wv+3), computes the
    // joint partial Aw = sum c*log2(c) - sum rk*log2(rk) and the per-wave
    // column-marginal partial colli[16] (each <= 576, fits u16).
    float Aw = 0.0f;
    int colli[16];
    #pragma unroll
    for (int i = 0; i < 16; ++i) colli[i] = 0;
    #pragma unroll
    for (int kk = 0; kk < 4; ++kk) {
        int k = (wv << 2) + kk;
        int rk = 0;
        #pragma unroll
        for (int q = 0; q < 4; ++q) {
            unsigned v = hist[(k << 8) + (q << 6) + tid];
            #pragma unroll
            for (int j = 0; j < 4; ++j) {
                int c = (int)((v >> (8*j)) & 0xFFu);
                rk += c;
                colli[(q << 2) + j] += c;
                if (c) Aw += (float)c * __log2f((float)c);
            }
        }
        if (rk) Aw -= (float)rk * __log2f((float)rk);
    }
    __syncthreads();   // ALL reads complete before hist is reused below

    // Phase 2: stage partials into the (dead) hist LDS.
    // coll words: [wv*512, wv*512+512)   (u16 pairs, 8 words/lane)
    // Aw bits:    [2048 + wv*64, +64)
    #pragma unroll
    for (int j = 0; j < 8; ++j)
        hist[(wv << 9) + (j << 6) + tid] =
            (unsigned)colli[2*j] | ((unsigned)colli[2*j+1] << 16);
    hist[2048 + (wv << 6) + tid] = __float_as_uint(Aw);
    __syncthreads();
    if (wv != 0) return;      // waves 1..3 done

    // Phase 3: wave0 reduces 4 partials per lane and finishes.
    float A = 0.0f;
    #pragma unroll
    for (int w = 0; w < 4; ++w) A += __uint_as_float(hist[2048 + (w << 6) + tid]);
    int coll[16];
    #pragma unroll
    for (int i = 0; i < 16; ++i) coll[i] = 0;
    #pragma unroll
    for (int w = 0; w < 4; ++w) {
        #pragma unroll
        for (int j = 0; j < 8; ++j) {
            unsigned u = hist[(w << 9) + (j << 6) + tid];
            coll[2*j]   += (int)(u & 0xFFFFu);
            coll[2*j+1] += (int)(u >> 16);
        }
    }
    int N = 0;
    #pragma unroll
    for (int i = 0; i < 16; ++i) {
        N += coll[i];
        if (coll[i]) A -= (float)coll[i] * __log2f((float)coll[i]);
    }
    float fN = (float)N;
    out[(b * IMH + Y0 + ty) * IMW + X0 + tx] = (A + fN * __log2f(fN)) * LN2F / fN;
}

extern "C" void kernel_launch(void* const* d_in, const int* in_sizes, int n_in,
                              void* d_out, int out_size, void* d_ws, size_t ws_size,
                              hipStream_t stream) {
    const float* im = (const float*)d_in[0];
    const float* tm = (const float*)d_in[1];
    float* out = (float*)d_out;
    unsigned char* pIm = (unsigned char*)d_ws;             // 373248 B
    unsigned* pT   = (unsigned*)((char*)d_ws + 373248);    // 2304 B
    unsigned* mnmx = (unsigned*)((char*)d_ws + 375552);    // 32 B
    // partials at the start of the pIm region: consumed by k_mm2 before
    // k_prep overwrites pIm (stream order).
    float2* partials = (float2*)d_ws;                      // 68 * 8 B

    k_mm1<<<68, 256, 0, stream>>>(im, tm, partials);
    k_mm2<<<1, 256, 0, stream>>>(partials, mnmx);
    k_prep<<<366, 256, 0, stream>>>(im, tm, mnmx, (unsigned*)pIm, pT);
    k_main<<<dim3(48, 48, 2), 256, 0, stream>>>(pIm, pT, out);
}

// Round 6
// 189.415 us; speedup vs baseline: 1.0589x; 1.0126x over previous
//
#include <hip/hip_runtime.h>

// FastCMIF: sliding-window mutual information via exact integer joint
// histograms (replaces the reference's 256 FFT convolutions).
//
// MI = (1/N)[ sum c_kl ln c_kl - sum c_k ln c_k - sum c_l ln c_l + N ln N ]
// OOB window pixels add 0 (border blocks), reproducing border clip + mask.
//
// R11: k_main is at ~97% of the LDS-atomic pipe floor (8.29 vs ~8 cyc per
// wave64 ds_add; 41472 wave-atomics/CU) -- untouched. Non-main time is
// ~49us for ~9us of real work (launch/gap overhead ~10us per dependent
// dispatch). This round: fuse k_mm2 INTO k_prep (each prep block inline
// re-reduces the 68 partials: 544B L2 reads, deterministic, no sync,
// bit-identical reduction order) -> 4 dispatches become 3. Partials move
// to the TAIL OF d_out (written by k_mm1, read by k_prep, fully
// overwritten by k_main afterwards; stream order guarantees each step) so
// prep's pIm writes can't race the partials reads and no workspace-size
// assumption is added. Also: interior prep words load im as one float4
// (px 4-aligned by construction); per-pixel IEEE div kept -> bins
// bit-identical.

#define IMH 384
#define IMW 384
#define TH 48
#define TW 48
#define PAD 24
#define PH 432
#define PIMG (PH*PH)        // 186624
#define NIMGW (PIMG/4)      // 46656 words
#define TOTW (2*NIMGW)      // 93312
#define FLTMAX 3.402823466e+38f
#define LN2F 0.69314718055994530942f

#if __has_builtin(__builtin_amdgcn_alignbyte)
#define ALIGNBYTE(hi,lo,s) __builtin_amdgcn_alignbyte((hi),(lo),(s))
#else
#define ALIGNBYTE(hi,lo,s) ((unsigned)(((((unsigned long long)(hi))<<32)|(unsigned long long)(lo)) >> ((s)*8)))
#endif

// ---- stage 1: wide min/max partial reduction (68 blocks, float4 loads) ----
// partials[b]: b<64 image slices (32 per image), b>=64 template halves.
__global__ void k_mm1(const float* __restrict__ im, const float* __restrict__ tm,
                      float2* __restrict__ partials) {
    int b = blockIdx.x;
    const float4* src; int cnt;
    if (b < 64) { src = (const float4*)(im + (b >> 5) * (IMH*IMW)) + (b & 31) * 1152; cnt = 1152; }
    else        { src = (const float4*)(tm + ((b - 64) >> 1) * (TH*TW)) + ((b - 64) & 1) * 288; cnt = 288; }
    float mn = FLTMAX, mx = -FLTMAX;
    for (int i = threadIdx.x; i < cnt; i += 256) {
        float4 v = src[i];
        mn = fminf(mn, fminf(fminf(v.x, v.y), fminf(v.z, v.w)));
        mx = fmaxf(mx, fmaxf(fmaxf(v.x, v.y), fmaxf(v.z, v.w)));
    }
    for (int o = 32; o > 0; o >>= 1) {
        mn = fminf(mn, __shfl_down(mn, o));
        mx = fmaxf(mx, __shfl_down(mx, o));
    }
    __shared__ float smn[4], smx[4];
    int w = threadIdx.x >> 6;
    if ((threadIdx.x & 63) == 0) { smn[w] = mn; smx[w] = mx; }
    __syncthreads();
    if (threadIdx.x == 0) {
        mn = fminf(fminf(smn[0], smn[1]), fminf(smn[2], smn[3]));
        mx = fmaxf(fmaxf(smx[0], smx[1]), fmaxf(smx[2], smx[3]));
        partials[b] = make_float2(mn, mx);
    }
}

// Fused (mm2 + bin+pad + template pack): every block re-reduces the 68
// partials inline (wave w: {im0, im1, t0, t1}), then does its prep slice.
__global__ void k_prep(const float* __restrict__ im, const float* __restrict__ tm,
                       const float2* __restrict__ partials,
                       unsigned* __restrict__ pImW, unsigned* __restrict__ pT) {
    __shared__ float smn[4], smx[4];
    {   // inline mm2: identical reduction structure/order -> identical bits
        int w = threadIdx.x >> 6, lane = threadIdx.x & 63;
        int cnt = (w < 2) ? 32 : 2;
        int idx = (w < 2) ? w * 32 + lane : 64 + (w - 2) * 2 + lane;
        float mn = FLTMAX, mx = -FLTMAX;
        if (lane < cnt) { float2 p = partials[idx]; mn = p.x; mx = p.y; }
        for (int o = 32; o > 0; o >>= 1) {
            mn = fminf(mn, __shfl_down(mn, o));
            mx = fmaxf(mx, __shfl_down(mx, o));
        }
        if (lane == 0) { smn[w] = mn; smx[w] = mx; }
    }
    __syncthreads();

    int blk = blockIdx.x;
    if (blk < 365) {
        int wi = blk * 256 + threadIdx.x;
        if (wi < TOTW) {
            int b = wi / NIMGW;
            int rem4 = (wi - b * NIMGW) * 4;
            int py = rem4 / PH;
            int px = rem4 - py * PH;          // always a multiple of 4
            float mn = smn[b], mx = smx[b];
            unsigned word = 0;
            if (py >= PAD && py < PAD + IMH && px >= PAD && px + 3 < PAD + IMW) {
                // fully interior word: one aligned float4 load (px-24 % 4 == 0)
                float4 v = *(const float4*)&im[b * (IMH*IMW) + (py - PAD) * IMW + (px - PAD)];
                // replicate reference numerics exactly: sub, IEEE div, mul 15, floor
                word  = ((unsigned)(int)floorf((v.x - mn) / (mx - mn) * 15.0f));
                word |= ((unsigned)(int)floorf((v.y - mn) / (mx - mn) * 15.0f)) << 8;
                word |= ((unsigned)(int)floorf((v.z - mn) / (mx - mn) * 15.0f)) << 16;
                word |= ((unsigned)(int)floorf((v.w - mn) / (mx - mn) * 15.0f)) << 24;
            } else {
                #pragma unroll
                for (int j = 0; j < 4; ++j) {
                    int x = px + j;
                    unsigned bin = 16u;          // sentinel: outside image
                    if (py >= PAD && py < PAD + IMH && x >= PAD && x < PAD + IMW) {
                        float v = im[b * (IMH*IMW) + (py - PAD) * IMW + (x - PAD)];
                        float r = (v - mn) / (mx - mn);
                        bin = (unsigned)(int)floorf(r * 15.0f);
                    }
                    word |= bin << (8*j);
                }
            }
            pImW[wi] = word;
        }
    } else {
        for (int t = threadIdx.x; t < 576; t += 256) {
            int b = t / 288, w = t - b * 288;
            float mn = smn[2 + b], mx = smx[2 + b];
            const float* tptr = tm + b * (TH*TW) + w * 8;
            unsigned word = 0;
            #pragma unroll
            for (int j = 0; j < 8; ++j) {
                float r = (tptr[j] - mn) / (mx - mn);
                word |= ((unsigned)(int)floorf(r * 15.0f)) << (4*j);
            }
            pT[b*288 + w] = word;
        }
    }
}

__device__ __forceinline__ void load_row(const uint2* rowp, int r, unsigned (&w)[14]) {
    const uint2* p = rowp + r * (PH / 8);
    #pragma unroll
    for (int i = 0; i < 7; ++i) { uint2 v = p[i]; w[2*i] = v.x; w[2*i+1] = v.y; }
}
__device__ __forceinline__ void load_t(const uint2* tp, int r, unsigned (&t)[6]) {
    const uint2* p = tp + r * 3;
    #pragma unroll
    for (int i = 0; i < 3; ++i) { uint2 v = p[i]; t[2*i] = v.x; t[2*i+1] = v.y; }
}

// One window row: 48 updates, no convergent ops inside the loop.
template<bool BORDER>
__device__ __forceinline__ void do_row(const unsigned (&w)[14], const unsigned (&t)[6],
                                       unsigned* __restrict__ hist, int tid,
                                       unsigned sh, bool sel) {
    unsigned wsel[13];
    #pragma unroll
    for (int i = 0; i < 13; ++i) wsel[i] = sel ? w[i+1] : w[i];
    unsigned a[12];   // a[i] bytes = image bins at window cols 4i..4i+3
    #pragma unroll
    for (int i = 0; i < 12; ++i) a[i] = ALIGNBYTE(wsel[i+1], wsel[i], sh);
    unsigned tq[6];   // once per row: SGPR-ize the (uniform) template words
    #pragma unroll
    for (int j = 0; j < 6; ++j)
        tq[j] = (unsigned)__builtin_amdgcn_readfirstlane((int)t[j]);

    #pragma unroll
    for (int c = 0; c < 48; ++c) {
        unsigned byteval = (a[c >> 2] >> ((c & 3) * 8)) & 0xFFu;  // VALU (v_bfe)
        unsigned l    = (tq[c >> 3] >> ((c & 7) * 4)) & 0xFu;     // SALU (tq uniform)
        unsigned soff = (l >> 2) << 6;                            // SALU
        unsigned sadd = 1u << ((l & 3u) << 3);                    // SALU
        if (BORDER) {
            unsigned bin   = byteval & 15u;
            unsigned adder = (byteval != 16u) ? sadd : 0u;        // v_cmp + cndmask
            atomicAdd(&hist[(bin << 8) + soff + tid], adder);
        } else {
            atomicAdd(&hist[(byteval << 8) + soff + tid], sadd);  // lshl+add3+mov+ds_add
        }
    }
}

// Each wave accumulates its 12-row quarter of the window into the SHARED hist.
template<bool BORDER>
__device__ __forceinline__ void accum_tile(const uint2* rowp, const uint2* tp,
                                           unsigned* __restrict__ hist, int tid,
                                           unsigned sh, bool sel) {
    unsigned w0[14], w1[14], t0[6], t1[6];
    load_row(rowp, 0, w0); load_t(tp, 0, t0);
    #pragma unroll 1
    for (int r = 0; r < 12; r += 2) {
        load_row(rowp, r + 1, w1); load_t(tp, r + 1, t1);   // r+1 <= 11 always
        do_row<BORDER>(w0, t0, hist, tid, sh, sel);
        if (r + 2 < 12) { load_row(rowp, r + 2, w0); load_t(tp, r + 2, t0); }
        do_row<BORDER>(w1, t1, hist, tid, sh, sel);
    }
}

__global__ __launch_bounds__(256, 4)
void k_main(const unsigned char* __restrict__ pIm, const unsigned* __restrict__ pT,
            float* __restrict__ out) {
    // u8-packed per-lane joint histograms: word = (bin*4 + l/4)*64 + tid,
    // byte = l&3. ONE 16 KiB histogram shared by all four waves; wave wv
    // accumulates window rows [12*wv, 12*wv+12).
    __shared__ unsigned hist[16 * 4 * 64];
    const int wv  = threadIdx.x >> 6;
    const int tid = threadIdx.x & 63;
    const int tx = tid & 7, ty = tid >> 3;
    const int b = blockIdx.z;
    const int X0 = blockIdx.x << 3, Y0 = blockIdx.y << 3;

    {   // zero; each wave clears a quarter; lane stride 4 words -> max 8-way
        uint4 z = {0u, 0u, 0u, 0u};
        #pragma unroll
        for (int i = 0; i < 4; ++i) ((uint4*)hist)[(wv * 4 + i) * 64 + tid] = z;
    }
    __syncthreads();

    const uint2* rowp = (const uint2*)(pIm + b * PIMG + (Y0 + ty + 12 * wv) * PH + X0);
    const uint2* tp   = (const uint2*)(pT + b * 288) + wv * 36;   // 3 uint2 per t-row
    const unsigned sh = tx & 3;
    const bool sel = (tx & 4) != 0;

    // interior iff no touched padded col/row can be sentinel: [X0,X0+56) in [24,408)
    const bool interior = (blockIdx.x >= 3) && (blockIdx.x <= 43) &&
                          (blockIdx.y >= 3) && (blockIdx.y <= 43);
    if (interior) accum_tile<false>(rowp, tp, hist, tid, sh, sel);
    else          accum_tile<true >(rowp, tp, hist, tid, sh, sel);

    __syncthreads();          // drains all waves' ds_adds (lgkmcnt) + orders

    // ---- parallel epilogue ----
    // Phase 1: wave wv reads its 4 k-rows (k = 4*wv..4*wv+3), computes the
    // joint partial Aw = sum c*log2(c) - sum rk*log2(rk) and the per-wave
    // column-marginal partial colli[16] (each <= 576, fits u16).
    float Aw = 0.0f;
    int colli[16];
    #pragma unroll
    for (int i = 0; i < 16; ++i) colli[i] = 0;
    #pragma unroll
    for (int kk = 0; kk < 4; ++kk) {
        int k = (wv << 2) + kk;
        int rk = 0;
        #pragma unroll
        for (int q = 0; q < 4; ++q) {
            unsigned v = hist[(k << 8) + (q << 6) + tid];
            #pragma unroll
            for (int j = 0; j < 4; ++j) {
                int c = (int)((v >> (8*j)) & 0xFFu);
                rk += c;
                colli[(q << 2) + j] += c;
                if (c) Aw += (float)c * __log2f((float)c);
            }
        }
        if (rk) Aw -= (float)rk * __log2f((float)rk);
    }
    __syncthreads();   // ALL reads complete before hist is reused below

    // Phase 2: stage partials into the (dead) hist LDS.
    // coll words: [wv*512, wv*512+512)   (u16 pairs, 8 words/lane)
    // Aw bits:    [2048 + wv*64, +64)
    #pragma unroll
    for (int j = 0; j < 8; ++j)
        hist[(wv << 9) + (j << 6) + tid] =
            (unsigned)colli[2*j] | ((unsigned)colli[2*j+1] << 16);
    hist[2048 + (wv << 6) + tid] = __float_as_uint(Aw);
    __syncthreads();
    if (wv != 0) return;      // waves 1..3 done

    // Phase 3: wave0 reduces 4 partials per lane and finishes.
    float A = 0.0f;
    #pragma unroll
    for (int w = 0; w < 4; ++w) A += __uint_as_float(hist[2048 + (w << 6) + tid]);
    int coll[16];
    #pragma unroll
    for (int i = 0; i < 16; ++i) coll[i] = 0;
    #pragma unroll
    for (int w = 0; w < 4; ++w) {
        #pragma unroll
        for (int j = 0; j < 8; ++j) {
            unsigned u = hist[(w << 9) + (j << 6) + tid];
            coll[2*j]   += (int)(u & 0xFFFFu);
            coll[2*j+1] += (int)(u >> 16);
        }
    }
    int N = 0;
    #pragma unroll
    for (int i = 0; i < 16; ++i) {
        N += coll[i];
        if (coll[i]) A -= (float)coll[i] * __log2f((float)coll[i]);
    }
    float fN = (float)N;
    out[(b * IMH + Y0 + ty) * IMW + X0 + tx] = (A + fN * __log2f(fN)) * LN2F / fN;
}

extern "C" void kernel_launch(void* const* d_in, const int* in_sizes, int n_in,
                              void* d_out, int out_size, void* d_ws, size_t ws_size,
                              hipStream_t stream) {
    const float* im = (const float*)d_in[0];
    const float* tm = (const float*)d_in[1];
    float* out = (float*)d_out;
    unsigned char* pIm = (unsigned char*)d_ws;             // 373248 B
    unsigned* pT   = (unsigned*)((char*)d_ws + 373248);    // 2304 B
    // partials live in the TAIL of d_out (1179648 B total): k_mm1 writes,
    // k_prep reads, k_main fully overwrites out afterwards (stream order).
    float2* partials = (float2*)((char*)d_out + 2*IMH*IMW*4 - 68*8);

    k_mm1<<<68, 256, 0, stream>>>(im, tm, partials);
    k_prep<<<366, 256, 0, stream>>>(im, tm, partials, (unsigned*)pIm, pT);
    k_main<<<dim3(48, 48, 2), 256, 0, stream>>>(pIm, pT, out);
}